// Round 6
// baseline (154.657 us; speedup 1.0000x reference)
//
#include <hip/hip_runtime.h>

// CrumbReconstructor R9: R3's proven occupancy point (6.1 waves/SIMD, G=2)
// with the per-row overhead stripped.
//
// R8 post-mortem: v_pk_*_f32 is HALF-RATE on gfx950 (wave64 packed f32 =
// 128 f32 lanes on a 32-lane ALU = 4cy vs 2cy scalar) -> packing saved
// instructions, zero cycles. dur flat 85->87 at -40% instrs proves it.
//
// Cross-round fit: issue efficiency tracks waves/SIMD (R3: 83% @6.1,
// R7: 55% @2.05); floors are inflated by fixed per-row overhead. So:
//  - G=2 keys/thread (R3's TLP point: 6272 waves = 24.5/CU = 6.1/SIMD)
//  - BLOCK=128 (2-wave blocks): 3136 blocks = 12.25/CU, 6% quantization
//    (R3's 4-wave blocks had 14%); LDS 9KB x 13 = 117KB -> full residency.
//  - named ping-pong, 4 rows/iter: prefetch lands in the OTHER named set,
//    zero rotation movs (R3 paid 9 movs/row).
//  - norm pair per 2 rows via one ds_read_b64 (s_norm 8B-aligned).
// Floor: 142 instr/4 rows = 284cy; x64 iter x6.125 waves/SIMD = 46.4us
// @100% issue; at R3's 83% -> ~55us.
//
// Hot-loop math bit-identical to R3..R8 (absmax 0.0): rows scanned 0..255
// ascending; sequential fmaf dot; fmaf(dot,-2,knorm)+rn; strict <
// (first/lowest index wins exact ties = argmin).

#define LBLK 8          // memblock length
#define NROW 256        // codebook rows
#define BLOCK 128       // 2 waves per block
#define TPK 2           // keys per thread

typedef float f32x2 __attribute__((ext_vector_type(2)));

__global__ __launch_bounds__(BLOCK, 4) void crumb_kernel(
    const float* __restrict__ x,
    const float* __restrict__ mem,
    float* __restrict__ out,
    int nblocks)
{
    __shared__ float s_mem[NROW * LBLK];            // 8 KB, rows contiguous
    __shared__ __align__(8) float s_norm[NROW];     // 1 KB, b64-pair reads

    const int tid = threadIdx.x;

    // --- stage codebook: 2 rows per thread, coalesced ---
    {
        const float4* g = (const float4*)mem;
        #pragma unroll
        for (int c = 0; c < 2; ++c) {
            const int rr = c * BLOCK + tid;
            float4 a = g[rr * 2 + 0];
            float4 b = g[rr * 2 + 1];
            ((float4*)s_mem)[rr * 2 + 0] = a;
            ((float4*)s_mem)[rr * 2 + 1] = b;
            float q0 = a.x * a.x, q1 = a.y * a.y, q2 = a.z * a.z, q3 = a.w * a.w;
            float q4 = b.x * b.x, q5 = b.y * b.y, q6 = b.z * b.z, q7 = b.w * b.w;
            s_norm[rr] = ((q0 + q1) + (q2 + q3)) + ((q4 + q5) + (q6 + q7));
        }
    }
    __syncthreads();

    // --- load 2 keys per thread (coalesced per wave) ---
    const int lane = tid & 63;
    const int wid  = tid >> 6;
    const long base = (long)blockIdx.x * (BLOCK * TPK) + wid * (64 * TPK) + lane;

    float k0[LBLK], k1[LBLK];
    float kn0, kn1;
    long  kb0, kb1;
    bool  v0, v1;
    {
        long b0 = base;
        long b1 = base + 64;
        v0 = (b0 < (long)nblocks);
        v1 = (b1 < (long)nblocks);
        kb0 = v0 ? b0 : 0;
        kb1 = v1 ? b1 : 0;
        const float4* g0 = (const float4*)(x + kb0 * LBLK);
        const float4* g1 = (const float4*)(x + kb1 * LBLK);
        float4 a = g0[0], b = g0[1];
        k0[0] = a.x; k0[1] = a.y; k0[2] = a.z; k0[3] = a.w;
        k0[4] = b.x; k0[5] = b.y; k0[6] = b.z; k0[7] = b.w;
        float q0 = a.x * a.x, q1 = a.y * a.y, q2 = a.z * a.z, q3 = a.w * a.w;
        float q4 = b.x * b.x, q5 = b.y * b.y, q6 = b.z * b.z, q7 = b.w * b.w;
        kn0 = ((q0 + q1) + (q2 + q3)) + ((q4 + q5) + (q6 + q7));
        a = g1[0]; b = g1[1];
        k1[0] = a.x; k1[1] = a.y; k1[2] = a.z; k1[3] = a.w;
        k1[4] = b.x; k1[5] = b.y; k1[6] = b.z; k1[7] = b.w;
        q0 = a.x * a.x; q1 = a.y * a.y; q2 = a.z * a.z; q3 = a.w * a.w;
        q4 = b.x * b.x; q5 = b.y * b.y; q6 = b.z * b.z; q7 = b.w * b.w;
        kn1 = ((q0 + q1) + (q2 + q3)) + ((q4 + q5) + (q6 + q7));
    }

    float best0 = 3.4e38f, best1 = 3.4e38f;
    int   bidx0 = 0,       bidx1 = 0;

    // one row scored for both keys; bit-identical sequential chains
#define SCORE_ROW(RA, RB, RN, M)                                        \
    {                                                                   \
        float dot = k0[0] * (RA).x;                                     \
        dot = fmaf(k0[1], (RA).y, dot);                                 \
        dot = fmaf(k0[2], (RA).z, dot);                                 \
        dot = fmaf(k0[3], (RA).w, dot);                                 \
        dot = fmaf(k0[4], (RB).x, dot);                                 \
        dot = fmaf(k0[5], (RB).y, dot);                                 \
        dot = fmaf(k0[6], (RB).z, dot);                                 \
        dot = fmaf(k0[7], (RB).w, dot);                                 \
        float d = fmaf(dot, -2.0f, kn0) + (RN);                         \
        if (d < best0) { best0 = d; bidx0 = (M); }                      \
        float e = k1[0] * (RA).x;                                       \
        e = fmaf(k1[1], (RA).y, e);                                     \
        e = fmaf(k1[2], (RA).z, e);                                     \
        e = fmaf(k1[3], (RA).w, e);                                     \
        e = fmaf(k1[4], (RB).x, e);                                     \
        e = fmaf(k1[5], (RB).y, e);                                     \
        e = fmaf(k1[6], (RB).z, e);                                     \
        e = fmaf(k1[7], (RB).w, e);                                     \
        float f = fmaf(e, -2.0f, kn1) + (RN);                           \
        if (f < best1) { best1 = f; bidx1 = (M); }                      \
    }

    const float4* sm4 = (const float4*)s_mem;

    // preload rows 0,1 into set X
    float4 xa0 = sm4[0], xb0 = sm4[1];
    float4 xa1 = sm4[2], xb1 = sm4[3];
    f32x2  xn  = *(const f32x2*)&s_norm[0];

    // 4 rows per iteration, two named sets alternate -> no rotation movs
    for (int r = 0; r < NROW; r += 4) {
        const int r2 = (r + 2) & (NROW - 1);
        // prefetch rows r+2,r+3 into set Y
        float4 ya0 = sm4[r2 * 2 + 0], yb0 = sm4[r2 * 2 + 1];
        float4 ya1 = sm4[r2 * 2 + 2], yb1 = sm4[r2 * 2 + 3];
        f32x2  yn  = *(const f32x2*)&s_norm[r2];
        // compute rows r, r+1 from set X
        SCORE_ROW(xa0, xb0, xn.x, r);
        SCORE_ROW(xa1, xb1, xn.y, r + 1);
        // prefetch rows r+4,r+5 into set X (wraps to row 0 at end; unused)
        const int r4 = (r + 4) & (NROW - 1);
        xa0 = sm4[r4 * 2 + 0]; xb0 = sm4[r4 * 2 + 1];
        xa1 = sm4[r4 * 2 + 2]; xb1 = sm4[r4 * 2 + 3];
        xn  = *(const f32x2*)&s_norm[r4];
        // compute rows r+2, r+3 from set Y
        SCORE_ROW(ya0, yb0, yn.x, r2);
        SCORE_ROW(ya1, yb1, yn.y, r2 + 1);
    }
#undef SCORE_ROW

    // --- gather winning rows from LDS, store ---
    if (v0) {
        float4* o = (float4*)(out + kb0 * LBLK);
        o[0] = sm4[bidx0 * 2 + 0];
        o[1] = sm4[bidx0 * 2 + 1];
    }
    if (v1) {
        float4* o = (float4*)(out + kb1 * LBLK);
        o[0] = sm4[bidx1 * 2 + 0];
        o[1] = sm4[bidx1 * 2 + 1];
    }
}

extern "C" void kernel_launch(void* const* d_in, const int* in_sizes, int n_in,
                              void* d_out, int out_size, void* d_ws, size_t ws_size,
                              hipStream_t stream) {
    const float* x   = (const float*)d_in[0];
    const float* mem = (const float*)d_in[1];
    float* out = (float*)d_out;

    int n = in_sizes[0];            // total x elements
    int nblocks = n / LBLK;         // key-blocks (802816 for std shape)
    int grid = (nblocks + BLOCK * TPK - 1) / (BLOCK * TPK);   // 3136

    hipLaunchKernelGGL(crumb_kernel, dim3(grid), dim3(BLOCK), 0, stream,
                       x, mem, out, nblocks);
}

// Round 7
// 132.449 us; speedup vs baseline: 1.1677x; 1.1677x over previous
//
#include <hip/hip_runtime.h>

// CrumbReconstructor R10: R3's proven scan structure + row-space split
// across wave pairs. Same waves/SIMD, 18% fewer instructions per key-row.
//
// R9 post-mortem: VGPR=32 proves the compiler discarded the named ping-pong
// (needs 32 regs of row data alone), sank ds_reads to uses, exposed LDS
// latency -> 94us. Keep R3's rotation idiom (compiles well: VGPR 36).
//
// Model (fits R0..R9): LDS broadcast reads are cheap (~4cy, same-address);
// R3 is VALU-ISSUE bound: 38 instr/row/wave x 2cy -> 50us floor at 6.1
// waves/SIMD, 71 measured = ~70% issue eff. Lever: amortize the 15-instr
// per-row overhead (3 LDS + 9 movs + loop) over 4 keys instead of 2 WITHOUT
// dropping waves: wave0 scans rows 0..127, wave1 rows 128..255, both for the
// SAME 256 keys (TPK=4). 6272 waves total (6.1/SIMD, as R3); BLOCK=128 ->
// 3136 blocks = 12.25/CU (6% quantization vs R3's 14%).
//
// Exactness: each row's distance is independent; split-scan + merge with
// strict (d_hi < d_lo) == full-scan argmin (hi row indices are strictly
// larger, ties keep lo = first index). Per-row math bit-identical to R3
// (absmax 0.0): sequential fmaf dot, fmaf(dot,-2,knorm)+rn, strict <.

#define LBLK 8          // memblock length
#define NROW 256        // codebook rows
#define HROW 128        // rows per wave (half of the row space)
#define BLOCK 128       // 2 waves per block (a lo/hi row pair)
#define TPK 4           // keys per thread; block covers 256 keys

__global__ __launch_bounds__(BLOCK, 6) void crumb_kernel(
    const float* __restrict__ x,
    const float* __restrict__ mem,
    float* __restrict__ out,
    int nblocks)
{
    __shared__ float s_mem[NROW * LBLK];   // 8 KB, rows contiguous
    __shared__ float s_norm[NROW];         // 1 KB
    __shared__ float s_hbest[256];         // hi-wave best per key
    __shared__ int   s_hbidx[256];         // hi-wave argmin per key

    const int tid = threadIdx.x;

    // --- stage codebook: 2 rows per thread, coalesced (R3-proven) ---
    {
        const float4* g = (const float4*)mem;
        #pragma unroll
        for (int c = 0; c < 2; ++c) {
            const int rr = c * BLOCK + tid;
            float4 a = g[rr * 2 + 0];
            float4 b = g[rr * 2 + 1];
            ((float4*)s_mem)[rr * 2 + 0] = a;
            ((float4*)s_mem)[rr * 2 + 1] = b;
            float q0 = a.x * a.x, q1 = a.y * a.y, q2 = a.z * a.z, q3 = a.w * a.w;
            float q4 = b.x * b.x, q5 = b.y * b.y, q6 = b.z * b.z, q7 = b.w * b.w;
            s_norm[rr] = ((q0 + q1) + (q2 + q3)) + ((q4 + q5) + (q6 + q7));
        }
    }
    __syncthreads();

    const int lane = tid & 63;
    const int wid  = tid >> 6;      // 0: rows 0..127 + merge/store, 1: rows 128..255

    // --- load the block's 256 keys (both waves load the same keys) ---
    float k[TPK][LBLK];
    float knorm[TPK];
    long  kb[TPK];
    bool  valid[TPK];

    #pragma unroll
    for (int t = 0; t < TPK; ++t) {
        long b0 = (long)blockIdx.x * 256 + t * 64 + lane;
        valid[t] = (b0 < (long)nblocks);
        kb[t] = valid[t] ? b0 : 0;
        const float4* g = (const float4*)(x + kb[t] * LBLK);
        float4 a = g[0], b = g[1];
        k[t][0] = a.x; k[t][1] = a.y; k[t][2] = a.z; k[t][3] = a.w;
        k[t][4] = b.x; k[t][5] = b.y; k[t][6] = b.z; k[t][7] = b.w;
        float q0 = a.x * a.x, q1 = a.y * a.y, q2 = a.z * a.z, q3 = a.w * a.w;
        float q4 = b.x * b.x, q5 = b.y * b.y, q6 = b.z * b.z, q7 = b.w * b.w;
        knorm[t] = ((q0 + q1) + (q2 + q3)) + ((q4 + q5) + (q6 + q7));
    }

    float best[TPK];
    int   bidx[TPK];
    #pragma unroll
    for (int t = 0; t < TPK; ++t) { best[t] = 3.4e38f; bidx[t] = 0; }

    // --- scan this wave's 128 rows; R3's rotation prefetch, 1 row ahead ---
    const int rbase = wid * HROW;
    const float4* sm4 = (const float4*)s_mem;

    float4 ra = sm4[rbase * 2 + 0];
    float4 rb = sm4[rbase * 2 + 1];
    float  rn = s_norm[rbase];

    #pragma unroll 4
    for (int r = 0; r < HROW; ++r) {
        const int rr = rbase + ((r + 1) & (HROW - 1));   // wraps in-half; unused on last
        float4 na = sm4[rr * 2 + 0];
        float4 nb = sm4[rr * 2 + 1];
        float  nn = s_norm[rr];
        const int m = rbase + r;

        #pragma unroll
        for (int t = 0; t < TPK; ++t) {
            float dot = k[t][0] * ra.x;
            dot = fmaf(k[t][1], ra.y, dot);
            dot = fmaf(k[t][2], ra.z, dot);
            dot = fmaf(k[t][3], ra.w, dot);
            dot = fmaf(k[t][4], rb.x, dot);
            dot = fmaf(k[t][5], rb.y, dot);
            dot = fmaf(k[t][6], rb.z, dot);
            dot = fmaf(k[t][7], rb.w, dot);
            float d = fmaf(dot, -2.0f, knorm[t]) + rn;
            // strict < : first (lowest) index wins exact ties (= argmin)
            if (d < best[t]) { best[t] = d; bidx[t] = m; }
        }

        ra = na; rb = nb; rn = nn;
    }

    // --- merge halves: hi wave publishes, lo wave combines (strict <) ---
    if (wid == 1) {
        #pragma unroll
        for (int t = 0; t < TPK; ++t) {
            s_hbest[t * 64 + lane] = best[t];
            s_hbidx[t * 64 + lane] = bidx[t];
        }
    }
    __syncthreads();

    if (wid == 0) {
        #pragma unroll
        for (int t = 0; t < TPK; ++t) {
            float dh = s_hbest[t * 64 + lane];
            int   bh = s_hbidx[t * 64 + lane];
            // hi indices are strictly larger: replace only on strictly smaller
            // distance -> exact first-min (argmin) semantics.
            if (dh < best[t]) { best[t] = dh; bidx[t] = bh; }
            if (valid[t]) {
                float4* o = (float4*)(out + kb[t] * LBLK);
                o[0] = sm4[bidx[t] * 2 + 0];
                o[1] = sm4[bidx[t] * 2 + 1];
            }
        }
    }
}

extern "C" void kernel_launch(void* const* d_in, const int* in_sizes, int n_in,
                              void* d_out, int out_size, void* d_ws, size_t ws_size,
                              hipStream_t stream) {
    const float* x   = (const float*)d_in[0];
    const float* mem = (const float*)d_in[1];
    float* out = (float*)d_out;

    int n = in_sizes[0];            // total x elements
    int nblocks = n / LBLK;         // key-blocks (802816 for std shape)
    int grid = (nblocks + 255) / 256;   // 3136 for std shape

    hipLaunchKernelGGL(crumb_kernel, dim3(grid), dim3(BLOCK), 0, stream,
                       x, mem, out, nblocks);
}